// Round 1
// baseline (8594.715 us; speedup 1.0000x reference)
//
#include <hip/hip_runtime.h>
#include <hip/hip_bf16.h>

// BiLSTM-CRF loss, MI355X. B=64 T=512 V=30000 E=256 H=512 C=9.
// Pipeline: pack weights/x (bf16) -> persistent flag-synced LSTM (MFMA) ->
// emission GEMM -> CRF forward -> reduce.

using short8 = __attribute__((ext_vector_type(8))) short;   // 8 x bf16 bits
using f32x4  = __attribute__((ext_vector_type(4))) float;

#define TT 512
#define BB 64

__device__ __forceinline__ unsigned short f2bf(float f) {
  unsigned int u = __builtin_bit_cast(unsigned int, f);
  u += 0x7FFFu + ((u >> 16) & 1u);           // RNE
  return (unsigned short)(u >> 16);
}
__device__ __forceinline__ float bf2f(short s) {
  unsigned int u = ((unsigned int)(unsigned short)s) << 16;
  return __builtin_bit_cast(float, u);
}
__device__ __forceinline__ float fast_rcp(float x) { return __builtin_amdgcn_rcpf(x); }
__device__ __forceinline__ float sigmoid_f(float x) { return fast_rcp(1.f + __expf(-x)); }
__device__ __forceinline__ float tanh_f(float x) {
  float e = __expf(-2.f * fabsf(x));
  float r = (1.f - e) * fast_rcp(1.f + e);
  return copysignf(r, x);
}
#define SEL4(i, a0, a1, a2, a3) ((i)==0?(a0):((i)==1?(a1):((i)==2?(a2):(a3))))

// ---------------- K0a: pack LSTM weights to bf16, gate-interleaved ----------
// Block bid (0..63): d=bid&1 (dir), sl=bid>>1 (slice of 16 hidden units).
// Column n in [0,64): jj=n>>2 (hidden unit), g=n&3 (gate i,f,g,o) ->
// weight row r = g*512 + sl*16 + jj.
__global__ void pack_weights(const float* __restrict__ Wih_f, const float* __restrict__ Whh_f,
                             const float* __restrict__ Wih_b, const float* __restrict__ Whh_b,
                             short* __restrict__ WpackX, short* __restrict__ WpackH) {
  const int bid = blockIdx.x;
  const int d = bid & 1, sl = bid >> 1;
  const float* Wih = d ? Wih_b : Wih_f;
  const float* Whh = d ? Whh_b : Whh_f;
  for (int idx = threadIdx.x; idx < 64 * 256; idx += 256) {
    int n = idx >> 8, k = idx & 255;
    int r = (n & 3) * 512 + sl * 16 + (n >> 2);
    WpackX[((size_t)bid * 64 + n) * 256 + k] = (short)f2bf(Wih[(size_t)r * 256 + k]);
  }
  for (int idx = threadIdx.x; idx < 64 * 512; idx += 256) {
    int n = idx >> 9, k = idx & 511;
    int r = (n & 3) * 512 + sl * 16 + (n >> 2);
    WpackH[((size_t)bid * 64 + n) * 512 + k] = (short)f2bf(Whh[(size_t)r * 512 + k]);
  }
}

// ---------------- K0b: gather embeddings into MFMA A-fragment layout --------
// xpack[t][mtile(4)][kc(8)][lane(64)] : 8 bf16 each.
// lane encodes row (b = mtile*16 + (lane&15)) and k = kc*32 + (lane>>4)*8.
__global__ void pack_x(const int* __restrict__ x, const float* __restrict__ emb,
                       short* __restrict__ xpack) {
  int gid = blockIdx.x * 256 + threadIdx.x;     // < 1048576
  int lane = gid & 63;
  int kc = (gid >> 6) & 7;
  int mt = (gid >> 9) & 3;
  int t  = gid >> 11;
  int b  = mt * 16 + (lane & 15);
  int k0 = kc * 32 + (lane >> 4) * 8;
  int vid = x[b * TT + t];
  const float* e = emb + (size_t)vid * 256 + k0;
  short8 v;
#pragma unroll
  for (int i = 0; i < 8; ++i) v[i] = (short)f2bf(e[i]);
  *reinterpret_cast<short8*>(xpack + (size_t)gid * 8) = v;
}

// ---------------- K0c: zero h ping-pong buffers + flags ---------------------
__global__ void init_state(short* __restrict__ hping, int* __restrict__ flags) {
  int gid = blockIdx.x * 256 + threadIdx.x;
  int* hp = (int*)hping;                         // 2*2*64*512 shorts = 65536 ints
  for (int i = gid; i < 65536; i += 64 * 256) hp[i] = 0;
  if (gid < 64) flags[gid] = 0;
}

// ---------------- K1: persistent flag-synced BiLSTM -------------------------
// 64 WGs x 256 thr. WG: d=bid&1, sl=bid>>1 owns hidden units [sl*16, sl*16+16)
// (x4 gates = 64 output cols). Whh slice register-resident; Wih slice in LDS.
// Per step: x-MFMA (no dep) -> wait all 32 slice flags -> h-MFMA ->
// shuffle gate exchange -> activations (c,h in regs) -> publish h + flag.
__launch_bounds__(256, 1)
__global__ void lstm_step_kernel(const short8* __restrict__ xpack,
                                 const short* __restrict__ WpackX,
                                 const short* __restrict__ WpackH,
                                 short* __restrict__ hping,   // [2][2][64][512]
                                 int* __restrict__ flags,     // [2][32]
                                 short* __restrict__ hhist,   // [2][512][64][512]
                                 const float* __restrict__ b_f,
                                 const float* __restrict__ b_b,
                                 const int* __restrict__ seq_len) {
  const int bid = blockIdx.x;
  const int d = bid & 1;
  const int sl = bid >> 1;
  const int tid = threadIdx.x;
  const int wv = tid >> 6;
  const int lane = tid & 63;
  const int l15 = lane & 15;
  const int lhi = lane >> 4;
  const int q = lane & 3;          // gate id of this lane's column
  const int jq = l15 >> 2;
  const int mtb = wv & 1;          // wave's M half
  const int nt = wv >> 1;          // wave's N half
  const int mbase = mtb * 32;
  const int nbase = nt * 32;

  __shared__ short wih[64 * 264];  // Wih slice, padded stride (264) vs bank conflicts
  for (int idx = tid; idx < 64 * 32; idx += 256) {
    int n = idx >> 5, c8 = idx & 31;
    short8 v = *reinterpret_cast<const short8*>(WpackX + ((size_t)bid * 64 + n) * 256 + c8 * 8);
    *reinterpret_cast<short8*>(&wih[n * 264 + c8 * 8]) = v;
  }

  // Whh B-fragments, register-resident for the whole kernel (2 tj x 16 kc).
  short8 bfh[2][16];
#pragma unroll
  for (int tj = 0; tj < 2; ++tj) {
#pragma unroll
    for (int kc = 0; kc < 16; ++kc) {
      int n = nbase + tj * 16 + l15;
      bfh[tj][kc] = *reinterpret_cast<const short8*>(
          WpackH + ((size_t)bid * 64 + n) * 512 + kc * 32 + lhi * 8);
    }
  }

  const float* bias = d ? b_b : b_f;
  float bi[2], bfg[2], bgg[2], bog[2];
  int jglob[2];
#pragma unroll
  for (int tj = 0; tj < 2; ++tj) {
    int jj = nt * 8 + tj * 4 + jq;
    int jg = sl * 16 + jj;
    jglob[tj] = jg;
    bi[tj]  = bias[jg];
    bfg[tj] = bias[512 + jg];
    bgg[tj] = bias[1024 + jg];
    bog[tj] = bias[1536 + jg];
  }
  int brow[2], Lr[2];
#pragma unroll
  for (int ti = 0; ti < 2; ++ti) {
    brow[ti] = mbase + ti * 16 + lhi * 4 + q;   // this lane's batch row (C/D row q)
    Lr[ti] = seq_len[brow[ti]];
  }
  float cst[2][2] = {{0.f, 0.f}, {0.f, 0.f}};
  float hst[2][2] = {{0.f, 0.f}, {0.f, 0.f}};

  int* myflags = flags + d * 32;
  __syncthreads();

  for (int s = 0; s < TT; ++s) {
    const int t = d ? (TT - 1 - s) : s;
    f32x4 acc[2][2];
#pragma unroll
    for (int ti = 0; ti < 2; ++ti)
#pragma unroll
      for (int tj = 0; tj < 2; ++tj) acc[ti][tj] = (f32x4){0.f, 0.f, 0.f, 0.f};

    // ---- x@Wih^T : no sequential dependency, hides the flag wait ----
    const short8* xp = xpack + (size_t)t * 2048;
#pragma unroll
    for (int kc = 0; kc < 8; ++kc) {
      short8 af[2], bf[2];
#pragma unroll
      for (int ti = 0; ti < 2; ++ti) {
        int mtile = mtb * 2 + ti;
        af[ti] = xp[(mtile * 8 + kc) * 64 + lane];
      }
#pragma unroll
      for (int tj = 0; tj < 2; ++tj) {
        int n = nbase + tj * 16 + l15;
        bf[tj] = *reinterpret_cast<const short8*>(&wih[n * 264 + kc * 32 + lhi * 8]);
      }
#pragma unroll
      for (int ti = 0; ti < 2; ++ti)
#pragma unroll
        for (int tj = 0; tj < 2; ++tj)
          acc[ti][tj] = __builtin_amdgcn_mfma_f32_16x16x32_bf16(af[ti], bf[tj], acc[ti][tj], 0, 0, 0);
    }

    // ---- wait until all 32 slices of h version s are published ----
    if (lane < 32) {
      int spins = 0;
      while (__hip_atomic_load(&myflags[lane], __ATOMIC_ACQUIRE, __HIP_MEMORY_SCOPE_AGENT) < s) {
        __builtin_amdgcn_s_sleep(1);
        if (++spins > (1 << 20)) break;      // anti-hang safety valve
      }
    }
    __threadfence();   // acquire for whole wave before reading h

    // ---- h@Whh^T ----
    const short* hp = hping + ((size_t)(d * 2 + (s & 1)) * 64) * 512;
#pragma unroll
    for (int kc = 0; kc < 16; ++kc) {
      short8 af[2];
#pragma unroll
      for (int ti = 0; ti < 2; ++ti)
        af[ti] = *reinterpret_cast<const short8*>(hp + (mbase + ti * 16 + l15) * 512 + kc * 32 + lhi * 8);
#pragma unroll
      for (int ti = 0; ti < 2; ++ti)
#pragma unroll
        for (int tj = 0; tj < 2; ++tj)
          acc[ti][tj] = __builtin_amdgcn_mfma_f32_16x16x32_bf16(af[ti], bfh[tj][kc], acc[ti][tj], 0, 0, 0);
    }

    // ---- epilogue: gather i,f,g,o via 4-lane shuffles, update state ----
    short* hpo = hping + ((size_t)(d * 2 + ((s + 1) & 1)) * 64) * 512;
#pragma unroll
    for (int ti = 0; ti < 2; ++ti) {
#pragma unroll
      for (int tj = 0; tj < 2; ++tj) {
        f32x4 A = acc[ti][tj];
        float a0 = A[0], a1 = A[1], a2 = A[2], a3 = A[3];
        float e10 = __shfl_xor(a0, 1, 64), e11 = __shfl_xor(a1, 1, 64),
              e12 = __shfl_xor(a2, 1, 64), e13 = __shfl_xor(a3, 1, 64);
        float e20 = __shfl_xor(a0, 2, 64), e21 = __shfl_xor(a1, 2, 64),
              e22 = __shfl_xor(a2, 2, 64), e23 = __shfl_xor(a3, 2, 64);
        float e30 = __shfl_xor(a0, 3, 64), e31 = __shfl_xor(a1, 3, 64),
              e32 = __shfl_xor(a2, 3, 64), e33 = __shfl_xor(a3, 3, 64);
        // g_[e] = gate (q^e) value at this lane's row q
        float g0 = SEL4(q, a0, a1, a2, a3);
        float g1 = SEL4(q, e10, e11, e12, e13);
        float g2 = SEL4(q, e20, e21, e22, e23);
        float g3 = SEL4(q, e30, e31, e32, e33);
        float gi = SEL4(q,     g0, g1, g2, g3) + bi[tj];
        float gf = SEL4(q ^ 1, g0, g1, g2, g3) + bfg[tj];
        float gg = SEL4(q ^ 2, g0, g1, g2, g3) + bgg[tj];
        float go = SEL4(q ^ 3, g0, g1, g2, g3) + bog[tj];
        float si = sigmoid_f(gi), sf = sigmoid_f(gf), so = sigmoid_f(go);
        float ct = sf * cst[ti][tj] + si * tanh_f(gg);
        float ht = so * tanh_f(ct);
        bool m = (t < Lr[ti]);
        float cn = m ? ct : cst[ti][tj];
        float hn = m ? ht : hst[ti][tj];
        cst[ti][tj] = cn;
        hst[ti][tj] = hn;
        hpo[brow[ti] * 512 + jglob[tj]] = (short)f2bf(hn);                 // frozen carry
        hhist[(((size_t)d * TT + t) * 64 + brow[ti]) * 512 + jglob[tj]] =
            m ? (short)f2bf(ht) : (short)0;                                // masked output
      }
    }
    __syncthreads();
    if (tid == 0) {
      __threadfence();
      __hip_atomic_store(&myflags[sl], s + 1, __ATOMIC_RELEASE, __HIP_MEMORY_SCOPE_AGENT);
    }
  }
}

// ---------------- K2: emission logits = [hf|hb] @ Wfc^T ---------------------
__global__ void emis_kernel(const short* __restrict__ hhist,
                            const float* __restrict__ Wfc,
                            float* __restrict__ logits) {
  int gid = blockIdx.x * 256 + threadIdx.x;    // 32768*9 = 294912 threads
  int r = gid / 9;
  int c = gid - r * 9;
  int b = r >> 9, t = r & 511;
  const short8* hf = reinterpret_cast<const short8*>(hhist + ((size_t)t * 64 + b) * 512);
  const short8* hb = reinterpret_cast<const short8*>(hhist + ((size_t)(512 + t) * 64 + b) * 512);
  const f32x4* w0 = reinterpret_cast<const f32x4*>(Wfc + (size_t)c * 1024);
  const f32x4* w1 = reinterpret_cast<const f32x4*>(Wfc + (size_t)c * 1024 + 512);
  float acc = 0.f;
#pragma unroll 4
  for (int j8 = 0; j8 < 64; ++j8) {
    short8 v = hf[j8];
    f32x4 wa = w0[j8 * 2], wb = w0[j8 * 2 + 1];
    acc += bf2f(v[0]) * wa[0] + bf2f(v[1]) * wa[1] + bf2f(v[2]) * wa[2] + bf2f(v[3]) * wa[3]
         + bf2f(v[4]) * wb[0] + bf2f(v[5]) * wb[1] + bf2f(v[6]) * wb[2] + bf2f(v[7]) * wb[3];
  }
#pragma unroll 4
  for (int j8 = 0; j8 < 64; ++j8) {
    short8 v = hb[j8];
    f32x4 wa = w1[j8 * 2], wb = w1[j8 * 2 + 1];
    acc += bf2f(v[0]) * wa[0] + bf2f(v[1]) * wa[1] + bf2f(v[2]) * wa[2] + bf2f(v[3]) * wa[3]
         + bf2f(v[4]) * wb[0] + bf2f(v[5]) * wb[1] + bf2f(v[6]) * wb[2] + bf2f(v[7]) * wb[3];
  }
  logits[gid] = acc;
}

// ---------------- K3: CRF numerator + forward algorithm per batch -----------
__global__ void crf_kernel(const float* __restrict__ logits, const int* __restrict__ y,
                           const int* __restrict__ seq_len, const float* __restrict__ start_t,
                           const float* __restrict__ end_t, const float* __restrict__ trans,
                           float* __restrict__ partials) {
  const int b = blockIdx.x;
  const int lane = threadIdx.x;          // 64
  const float* lg = logits + (size_t)b * TT * 9;
  const int* yb = y + b * TT;
  const int L = seq_len[b];

  // numerator: sum over t of (emis[t][y_t] + trans[y_{t-1}][y_t]) for t < L
  float acc = 0.f;
  for (int t = lane; t < TT; t += 64) {
    if (t < L) {
      float mx = lg[t * 9];
      for (int c = 1; c < 9; ++c) mx = fmaxf(mx, lg[t * 9 + c]);
      float se = 0.f;
      for (int c = 0; c < 9; ++c) se += __expf(lg[t * 9 + c] - mx);
      float lse = mx + __logf(se);
      int yt = yb[t];
      acc += lg[t * 9 + yt] - lse;
      if (t >= 1) acc += trans[yb[t - 1] * 9 + yt];
    }
  }
#pragma unroll
  for (int off = 32; off >= 1; off >>= 1) acc += __shfl_down(acc, off, 64);

  // denominator: forward algorithm, lane c<9 carries score[c]
  const int c = (lane < 9) ? lane : 0;
  float score;
  {
    float mx = lg[0];
    for (int cc = 1; cc < 9; ++cc) mx = fmaxf(mx, lg[cc]);
    float se = 0.f;
    for (int cc = 0; cc < 9; ++cc) se += __expf(lg[cc] - mx);
    score = start_t[c] + lg[c] - (mx + __logf(se));
  }
  float tr[9];
#pragma unroll
  for (int cc = 0; cc < 9; ++cc) tr[cc] = trans[cc * 9 + c];
  for (int t = 1; t < L; ++t) {
    const float* lt = lg + t * 9;
    float mx2 = lt[0];
    for (int cc = 1; cc < 9; ++cc) mx2 = fmaxf(mx2, lt[cc]);
    float se2 = 0.f;
    for (int cc = 0; cc < 9; ++cc) se2 += __expf(lt[cc] - mx2);
    float em = lt[c] - (mx2 + __logf(se2));
    float vv[9];
    float mx = -1e30f;
#pragma unroll
    for (int cc = 0; cc < 9; ++cc) {
      float sp = __shfl(score, cc, 64);
      vv[cc] = sp + tr[cc];
      mx = fmaxf(mx, vv[cc]);
    }
    float se = 0.f;
#pragma unroll
    for (int cc = 0; cc < 9; ++cc) se += __expf(vv[cc] - mx);
    score = mx + __logf(se) + em;
  }
  float val = (lane < 9) ? (score + end_t[lane]) : -1e30f;
  float mm = val;
#pragma unroll
  for (int off = 1; off < 64; off <<= 1) mm = fmaxf(mm, __shfl_xor(mm, off, 64));
  float se = (lane < 9) ? __expf(val - mm) : 0.f;
#pragma unroll
  for (int off = 1; off < 64; off <<= 1) se += __shfl_xor(se, off, 64);
  float den = mm + __logf(se);
  if (lane == 0) {
    float num = acc + start_t[yb[0]] + end_t[yb[L - 1]];
    partials[b] = num - den;
  }
}

// ---------------- K4: final reduce ------------------------------------------
__global__ void finalize_kernel(const float* __restrict__ partials, float* __restrict__ out) {
  int l = threadIdx.x;
  float v = partials[l];
#pragma unroll
  for (int off = 32; off >= 1; off >>= 1) v += __shfl_down(v, off, 64);
  if (l == 0) out[0] = -v;
}

extern "C" void kernel_launch(void* const* d_in, const int* in_sizes, int n_in,
                              void* d_out, int out_size, void* d_ws, size_t ws_size,
                              hipStream_t stream) {
  const int*   x     = (const int*)d_in[0];
  const int*   seqln = (const int*)d_in[1];
  const int*   y     = (const int*)d_in[2];
  const float* emb   = (const float*)d_in[3];
  const float* Wih_f = (const float*)d_in[4];
  const float* Whh_f = (const float*)d_in[5];
  const float* b_f   = (const float*)d_in[6];
  const float* Wih_b = (const float*)d_in[7];
  const float* Whh_b = (const float*)d_in[8];
  const float* b_b   = (const float*)d_in[9];
  const float* Wfc   = (const float*)d_in[10];
  const float* st    = (const float*)d_in[11];
  const float* en    = (const float*)d_in[12];
  const float* trans = (const float*)d_in[13];
  float* out = (float*)d_out;

  char* ws = (char*)d_ws;                         // total required ~91.6 MB
  short* WpackX   = (short*)(ws + 0);             // 2,097,152
  short* WpackH   = (short*)(ws + 2097152);       // 4,194,304
  short* xpack    = (short*)(ws + 6291456);       // 16,777,216
  short* hping    = (short*)(ws + 23068672);      // 262,144
  int*   flags    = (int*)  (ws + 23330816);      // 256
  float* partials = (float*)(ws + 23331072);      // 256
  float* logits   = (float*)(ws + 23331328);      // 1,179,648
  short* hhist    = (short*)(ws + 24510976);      // 67,108,864 -> end 91,619,840

  pack_weights<<<64, 256, 0, stream>>>(Wih_f, Whh_f, Wih_b, Whh_b, WpackX, WpackH);
  pack_x<<<4096, 256, 0, stream>>>(x, emb, xpack);
  init_state<<<64, 256, 0, stream>>>(hping, flags);
  lstm_step_kernel<<<64, 256, 0, stream>>>((const short8*)xpack, WpackX, WpackH,
                                           hping, flags, hhist, b_f, b_b, seqln);
  emis_kernel<<<1152, 256, 0, stream>>>(hhist, Wfc, logits);
  crf_kernel<<<64, 64, 0, stream>>>(logits, y, seqln, st, en, trans, partials);
  finalize_kernel<<<1, 64, 0, stream>>>(partials, out);
}

// Round 2
// 6596.732 us; speedup vs baseline: 1.3029x; 1.3029x over previous
//
#include <hip/hip_runtime.h>
#include <hip/hip_bf16.h>

// BiLSTM-CRF loss, MI355X. B=64 T=512 V=30000 E=256 H=512 C=9.
// Round 2: fence-free flag sync (system-scope relaxed atomics = sc0 sc1
// write-through to coherence point; no buffer_wbl2 / buffer_inv per step),
// MFMA emission GEMM.

using short8 = __attribute__((ext_vector_type(8))) short;   // 8 x bf16 bits
using f32x4  = __attribute__((ext_vector_type(4))) float;
using ull2   = __attribute__((ext_vector_type(2))) unsigned long long;

#define TT 512
#define BB 64

__device__ __forceinline__ unsigned short f2bf(float f) {
  unsigned int u = __builtin_bit_cast(unsigned int, f);
  u += 0x7FFFu + ((u >> 16) & 1u);           // RNE
  return (unsigned short)(u >> 16);
}
__device__ __forceinline__ float bf2f(short s) {
  unsigned int u = ((unsigned int)(unsigned short)s) << 16;
  return __builtin_bit_cast(float, u);
}
__device__ __forceinline__ float fast_rcp(float x) { return __builtin_amdgcn_rcpf(x); }
__device__ __forceinline__ float sigmoid_f(float x) { return fast_rcp(1.f + __expf(-x)); }
__device__ __forceinline__ float tanh_f(float x) {
  float e = __expf(-2.f * fabsf(x));
  float r = (1.f - e) * fast_rcp(1.f + e);
  return copysignf(r, x);
}
#define SEL4(i, a0, a1, a2, a3) ((i)==0?(a0):((i)==1?(a1):((i)==2?(a2):(a3))))

// sc0+sc1 load of 16B (two relaxed system-scope 8B atomic loads; batchable).
__device__ __forceinline__ short8 load_h16(const short* p) {
  ull2 v;
  v[0] = __hip_atomic_load((const unsigned long long*)p, __ATOMIC_RELAXED,
                           __HIP_MEMORY_SCOPE_SYSTEM);
  v[1] = __hip_atomic_load((const unsigned long long*)p + 1, __ATOMIC_RELAXED,
                           __HIP_MEMORY_SCOPE_SYSTEM);
  return __builtin_bit_cast(short8, v);
}
__device__ __forceinline__ void store_h2(short* p, short v) {
  __hip_atomic_store(p, v, __ATOMIC_RELAXED, __HIP_MEMORY_SCOPE_SYSTEM);
}

// ---------------- K0a: pack LSTM + FC weights to bf16 -----------------------
// LSTM: block bid (0..63): d=bid&1, sl=bid>>1. Column n in [0,64): unit
// jj=n>>2, gate g=n&3 -> weight row r = g*512 + sl*16 + jj.
// FC: WfcPack[16][1024] bf16 (rows 9..15 zero), done by block 0.
__global__ void pack_weights(const float* __restrict__ Wih_f, const float* __restrict__ Whh_f,
                             const float* __restrict__ Wih_b, const float* __restrict__ Whh_b,
                             const float* __restrict__ Wfc,
                             short* __restrict__ WpackX, short* __restrict__ WpackH,
                             short* __restrict__ WfcPack) {
  const int bid = blockIdx.x;
  const int d = bid & 1, sl = bid >> 1;
  const float* Wih = d ? Wih_b : Wih_f;
  const float* Whh = d ? Whh_b : Whh_f;
  for (int idx = threadIdx.x; idx < 64 * 256; idx += 256) {
    int n = idx >> 8, k = idx & 255;
    int r = (n & 3) * 512 + sl * 16 + (n >> 2);
    WpackX[((size_t)bid * 64 + n) * 256 + k] = (short)f2bf(Wih[(size_t)r * 256 + k]);
  }
  for (int idx = threadIdx.x; idx < 64 * 512; idx += 256) {
    int n = idx >> 9, k = idx & 511;
    int r = (n & 3) * 512 + sl * 16 + (n >> 2);
    WpackH[((size_t)bid * 64 + n) * 512 + k] = (short)f2bf(Whh[(size_t)r * 512 + k]);
  }
  if (bid == 0) {
    for (int idx = threadIdx.x; idx < 16 * 1024; idx += 256) {
      int c = idx >> 10, k = idx & 1023;
      WfcPack[idx] = (c < 9) ? (short)f2bf(Wfc[c * 1024 + k]) : (short)0;
    }
  }
}

// ---------------- K0b: gather embeddings into MFMA A-fragment layout --------
// xpack[t][mtile(4)][kc(8)][lane(64)] : 8 bf16 each.
// lane encodes row (b = mtile*16 + (lane&15)) and k = kc*32 + (lane>>4)*8.
__global__ void pack_x(const int* __restrict__ x, const float* __restrict__ emb,
                       short* __restrict__ xpack) {
  int gid = blockIdx.x * 256 + threadIdx.x;     // < 1048576
  int lane = gid & 63;
  int kc = (gid >> 6) & 7;
  int mt = (gid >> 9) & 3;
  int t  = gid >> 11;
  int b  = mt * 16 + (lane & 15);
  int k0 = kc * 32 + (lane >> 4) * 8;
  int vid = x[b * TT + t];
  const float* e = emb + (size_t)vid * 256 + k0;
  short8 v;
#pragma unroll
  for (int i = 0; i < 8; ++i) v[i] = (short)f2bf(e[i]);
  *reinterpret_cast<short8*>(xpack + (size_t)gid * 8) = v;
}

// ---------------- K0c: zero flags -------------------------------------------
__global__ void init_state(int* __restrict__ flags) {
  if (threadIdx.x < 64) flags[threadIdx.x] = 0;
}

// ---------------- K1: persistent flag-synced BiLSTM -------------------------
// 64 WGs x 256 thr. WG: d=bid&1, sl=bid>>1 owns hidden units [sl*16, sl*16+16)
// (x4 gates = 64 output cols). Whh slice register-resident; Wih slice in LDS.
// Per step: x-MFMA (no dep, hides wait) -> spin on 32 slice flags (relaxed
// system atomics) -> h-MFMA from sc0sc1 loads -> shuffle gate exchange ->
// activations (c,h in regs) -> sc0sc1 publish h -> barrier (vmcnt drain) ->
// relaxed flag store. No cache-maintenance instructions anywhere in the loop.
__launch_bounds__(256, 1)
__global__ void lstm_step_kernel(const short8* __restrict__ xpack,
                                 const short* __restrict__ WpackX,
                                 const short* __restrict__ WpackH,
                                 short* __restrict__ hping,   // [2][2][64][512]
                                 int* __restrict__ flags,     // [2][32]
                                 short* __restrict__ hhist,   // [2][512][64][512]
                                 const float* __restrict__ b_f,
                                 const float* __restrict__ b_b,
                                 const int* __restrict__ seq_len) {
  const int bid = blockIdx.x;
  const int d = bid & 1;
  const int sl = bid >> 1;
  const int tid = threadIdx.x;
  const int wv = tid >> 6;
  const int lane = tid & 63;
  const int l15 = lane & 15;
  const int lhi = lane >> 4;
  const int q = lane & 3;          // gate id of this lane's column
  const int jq = l15 >> 2;
  const int mtb = wv & 1;          // wave's M half
  const int nt = wv >> 1;          // wave's N half
  const int mbase = mtb * 32;
  const int nbase = nt * 32;

  __shared__ short wih[64 * 264];  // Wih slice, padded stride vs bank conflicts
  for (int idx = tid; idx < 64 * 32; idx += 256) {
    int n = idx >> 5, c8 = idx & 31;
    short8 v = *reinterpret_cast<const short8*>(WpackX + ((size_t)bid * 64 + n) * 256 + c8 * 8);
    *reinterpret_cast<short8*>(&wih[n * 264 + c8 * 8]) = v;
  }

  // Whh B-fragments, register/AGPR-resident for the whole kernel.
  short8 bfh[2][16];
#pragma unroll
  for (int tj = 0; tj < 2; ++tj) {
#pragma unroll
    for (int kc = 0; kc < 16; ++kc) {
      int n = nbase + tj * 16 + l15;
      bfh[tj][kc] = *reinterpret_cast<const short8*>(
          WpackH + ((size_t)bid * 64 + n) * 512 + kc * 32 + lhi * 8);
    }
  }

  const float* bias = d ? b_b : b_f;
  float bi[2], bfg[2], bgg[2], bog[2];
  int jglob[2];
#pragma unroll
  for (int tj = 0; tj < 2; ++tj) {
    int jj = nt * 8 + tj * 4 + jq;
    int jg = sl * 16 + jj;
    jglob[tj] = jg;
    bi[tj]  = bias[jg];
    bfg[tj] = bias[512 + jg];
    bgg[tj] = bias[1024 + jg];
    bog[tj] = bias[1536 + jg];
  }
  int brow[2], Lr[2];
#pragma unroll
  for (int ti = 0; ti < 2; ++ti) {
    brow[ti] = mbase + ti * 16 + lhi * 4 + q;   // this lane's batch row (C/D row q)
    Lr[ti] = seq_len[brow[ti]];
  }
  float cst[2][2] = {{0.f, 0.f}, {0.f, 0.f}};
  float hst[2][2] = {{0.f, 0.f}, {0.f, 0.f}};

  int* myflags = flags + d * 32;
  __syncthreads();

  for (int s = 0; s < TT; ++s) {
    const int t = d ? (TT - 1 - s) : s;
    f32x4 acc[2][2];
#pragma unroll
    for (int ti = 0; ti < 2; ++ti)
#pragma unroll
      for (int tj = 0; tj < 2; ++tj) acc[ti][tj] = (f32x4){0.f, 0.f, 0.f, 0.f};

    // ---- x@Wih^T : no sequential dependency, hides the flag wait ----
    const short8* xp = xpack + (size_t)t * 2048;
#pragma unroll
    for (int kc = 0; kc < 8; ++kc) {
      short8 af[2], bf[2];
#pragma unroll
      for (int ti = 0; ti < 2; ++ti) {
        int mtile = mtb * 2 + ti;
        af[ti] = xp[(mtile * 8 + kc) * 64 + lane];
      }
#pragma unroll
      for (int tj = 0; tj < 2; ++tj) {
        int n = nbase + tj * 16 + l15;
        bf[tj] = *reinterpret_cast<const short8*>(&wih[n * 264 + kc * 32 + lhi * 8]);
      }
#pragma unroll
      for (int ti = 0; ti < 2; ++ti)
#pragma unroll
        for (int tj = 0; tj < 2; ++tj)
          acc[ti][tj] = __builtin_amdgcn_mfma_f32_16x16x32_bf16(af[ti], bf[tj], acc[ti][tj], 0, 0, 0);
    }

    if (s > 0) {
      // ---- wait until all 32 slices of h version s are published ----
      if (lane < 32) {
        int spins = 0;
        while (__hip_atomic_load(&myflags[lane], __ATOMIC_RELAXED,
                                 __HIP_MEMORY_SCOPE_SYSTEM) < s) {
          __builtin_amdgcn_s_sleep(1);
          if (++spins > (1 << 20)) break;      // anti-hang safety valve
        }
      }
      __builtin_amdgcn_sched_barrier(0);
      asm volatile("" ::: "memory");           // compiler fence: no load hoisting

      // ---- h@Whh^T (operands read at coherence point, no cache ops) ----
      const short* hp = hping + ((size_t)(d * 2 + (s & 1)) * 64) * 512;
#pragma unroll
      for (int kc = 0; kc < 16; ++kc) {
        short8 af[2];
#pragma unroll
        for (int ti = 0; ti < 2; ++ti)
          af[ti] = load_h16(hp + (mbase + ti * 16 + l15) * 512 + kc * 32 + lhi * 8);
#pragma unroll
        for (int ti = 0; ti < 2; ++ti)
#pragma unroll
          for (int tj = 0; tj < 2; ++tj)
            acc[ti][tj] = __builtin_amdgcn_mfma_f32_16x16x32_bf16(af[ti], bfh[tj][kc], acc[ti][tj], 0, 0, 0);
      }
    }

    // ---- epilogue: gather i,f,g,o via 4-lane shuffles, update state ----
    short* hpo = hping + ((size_t)(d * 2 + ((s + 1) & 1)) * 64) * 512;
#pragma unroll
    for (int ti = 0; ti < 2; ++ti) {
#pragma unroll
      for (int tj = 0; tj < 2; ++tj) {
        f32x4 A = acc[ti][tj];
        float a0 = A[0], a1 = A[1], a2 = A[2], a3 = A[3];
        float e10 = __shfl_xor(a0, 1, 64), e11 = __shfl_xor(a1, 1, 64),
              e12 = __shfl_xor(a2, 1, 64), e13 = __shfl_xor(a3, 1, 64);
        float e20 = __shfl_xor(a0, 2, 64), e21 = __shfl_xor(a1, 2, 64),
              e22 = __shfl_xor(a2, 2, 64), e23 = __shfl_xor(a3, 2, 64);
        float e30 = __shfl_xor(a0, 3, 64), e31 = __shfl_xor(a1, 3, 64),
              e32 = __shfl_xor(a2, 3, 64), e33 = __shfl_xor(a3, 3, 64);
        float g0 = SEL4(q, a0, a1, a2, a3);
        float g1 = SEL4(q, e10, e11, e12, e13);
        float g2 = SEL4(q, e20, e21, e22, e23);
        float g3 = SEL4(q, e30, e31, e32, e33);
        float gi = SEL4(q,     g0, g1, g2, g3) + bi[tj];
        float gf = SEL4(q ^ 1, g0, g1, g2, g3) + bfg[tj];
        float gg = SEL4(q ^ 2, g0, g1, g2, g3) + bgg[tj];
        float go = SEL4(q ^ 3, g0, g1, g2, g3) + bog[tj];
        float si = sigmoid_f(gi), sf = sigmoid_f(gf), so = sigmoid_f(go);
        float ct = sf * cst[ti][tj] + si * tanh_f(gg);
        float ht = so * tanh_f(ct);
        bool m = (t < Lr[ti]);
        float cn = m ? ct : cst[ti][tj];
        float hn = m ? ht : hst[ti][tj];
        cst[ti][tj] = cn;
        hst[ti][tj] = hn;
        store_h2(&hpo[brow[ti] * 512 + jglob[tj]], (short)f2bf(hn));       // frozen carry
        hhist[(((size_t)d * TT + t) * 64 + brow[ti]) * 512 + jglob[tj]] =
            m ? (short)f2bf(ht) : (short)0;                                // masked output
      }
    }
    // barrier drains vmcnt(0): all waves' sc-stores are acked at the
    // coherence point before the flag publish below.
    __syncthreads();
    if (tid == 0)
      __hip_atomic_store(&myflags[sl], s + 1, __ATOMIC_RELAXED,
                         __HIP_MEMORY_SCOPE_SYSTEM);
  }
}

// ---------------- K2: emission logits = [hf|hb] @ Wfc^T via MFMA ------------
// 256 blocks x 256 thr; wave handles 2 M-tiles of 16 rows (r = t*64+b).
__launch_bounds__(256)
__global__ void emis_kernel(const short* __restrict__ hhist,
                            const short* __restrict__ WfcPack,
                            float* __restrict__ logits) {
  __shared__ short wfc[16 * 1032];             // padded stride vs bank conflicts
  const int tid = threadIdx.x;
  for (int idx = tid; idx < 2048; idx += 256) {
    int n = idx >> 7, c8 = idx & 127;
    short8 v = *reinterpret_cast<const short8*>(WfcPack + n * 1024 + c8 * 8);
    *reinterpret_cast<short8*>(&wfc[n * 1032 + c8 * 8]) = v;
  }
  __syncthreads();
  const int wv = tid >> 6, lane = tid & 63;
  const int l15 = lane & 15, lhi = lane >> 4;
#pragma unroll
  for (int mt2 = 0; mt2 < 2; ++mt2) {
    int m = (blockIdx.x * 4 + wv) * 2 + mt2;
    int r0 = m * 16;
    f32x4 acc = (f32x4){0.f, 0.f, 0.f, 0.f};
#pragma unroll
    for (int kc = 0; kc < 32; ++kc) {
      const short* pa = hhist + ((kc < 16) ? 0 : (size_t)16777216)
                        + (size_t)(r0 + l15) * 512 + (kc & 15) * 32 + lhi * 8;
      short8 a = *reinterpret_cast<const short8*>(pa);
      short8 b = *reinterpret_cast<const short8*>(&wfc[l15 * 1032 + kc * 32 + lhi * 8]);
      acc = __builtin_amdgcn_mfma_f32_16x16x32_bf16(a, b, acc, 0, 0, 0);
    }
    int c = l15;
    if (c < 9) {
#pragma unroll
      for (int reg = 0; reg < 4; ++reg) {
        int rr = r0 + lhi * 4 + reg;
        int b = rr & 63, t = rr >> 6;
        logits[((size_t)b * TT + t) * 9 + c] = acc[reg];
      }
    }
  }
}

// ---------------- K3: CRF numerator + forward algorithm per batch -----------
__global__ void crf_kernel(const float* __restrict__ logits, const int* __restrict__ y,
                           const int* __restrict__ seq_len, const float* __restrict__ start_t,
                           const float* __restrict__ end_t, const float* __restrict__ trans,
                           float* __restrict__ partials) {
  const int b = blockIdx.x;
  const int lane = threadIdx.x;          // 64
  const float* lg = logits + (size_t)b * TT * 9;
  const int* yb = y + b * TT;
  const int L = seq_len[b];

  float acc = 0.f;
  for (int t = lane; t < TT; t += 64) {
    if (t < L) {
      float mx = lg[t * 9];
      for (int c = 1; c < 9; ++c) mx = fmaxf(mx, lg[t * 9 + c]);
      float se = 0.f;
      for (int c = 0; c < 9; ++c) se += __expf(lg[t * 9 + c] - mx);
      float lse = mx + __logf(se);
      int yt = yb[t];
      acc += lg[t * 9 + yt] - lse;
      if (t >= 1) acc += trans[yb[t - 1] * 9 + yt];
    }
  }
#pragma unroll
  for (int off = 32; off >= 1; off >>= 1) acc += __shfl_down(acc, off, 64);

  const int c = (lane < 9) ? lane : 0;
  float score;
  {
    float mx = lg[0];
    for (int cc = 1; cc < 9; ++cc) mx = fmaxf(mx, lg[cc]);
    float se = 0.f;
    for (int cc = 0; cc < 9; ++cc) se += __expf(lg[cc] - mx);
    score = start_t[c] + lg[c] - (mx + __logf(se));
  }
  float tr[9];
#pragma unroll
  for (int cc = 0; cc < 9; ++cc) tr[cc] = trans[cc * 9 + c];
  for (int t = 1; t < L; ++t) {
    const float* lt = lg + t * 9;
    float mx2 = lt[0];
    for (int cc = 1; cc < 9; ++cc) mx2 = fmaxf(mx2, lt[cc]);
    float se2 = 0.f;
    for (int cc = 0; cc < 9; ++cc) se2 += __expf(lt[cc] - mx2);
    float em = lt[c] - (mx2 + __logf(se2));
    float vv[9];
    float mx = -1e30f;
#pragma unroll
    for (int cc = 0; cc < 9; ++cc) {
      float sp = __shfl(score, cc, 64);
      vv[cc] = sp + tr[cc];
      mx = fmaxf(mx, vv[cc]);
    }
    float se = 0.f;
#pragma unroll
    for (int cc = 0; cc < 9; ++cc) se += __expf(vv[cc] - mx);
    score = mx + __logf(se) + em;
  }
  float val = (lane < 9) ? (score + end_t[lane]) : -1e30f;
  float mm = val;
#pragma unroll
  for (int off = 1; off < 64; off <<= 1) mm = fmaxf(mm, __shfl_xor(mm, off, 64));
  float se = (lane < 9) ? __expf(val - mm) : 0.f;
#pragma unroll
  for (int off = 1; off < 64; off <<= 1) se += __shfl_xor(se, off, 64);
  float den = mm + __logf(se);
  if (lane == 0) {
    float num = acc + start_t[yb[0]] + end_t[yb[L - 1]];
    partials[b] = num - den;
  }
}

// ---------------- K4: final reduce ------------------------------------------
__global__ void finalize_kernel(const float* __restrict__ partials, float* __restrict__ out) {
  int l = threadIdx.x;
  float v = partials[l];
#pragma unroll
  for (int off = 32; off >= 1; off >>= 1) v += __shfl_down(v, off, 64);
  if (l == 0) out[0] = -v;
}

extern "C" void kernel_launch(void* const* d_in, const int* in_sizes, int n_in,
                              void* d_out, int out_size, void* d_ws, size_t ws_size,
                              hipStream_t stream) {
  const int*   x     = (const int*)d_in[0];
  const int*   seqln = (const int*)d_in[1];
  const int*   y     = (const int*)d_in[2];
  const float* emb   = (const float*)d_in[3];
  const float* Wih_f = (const float*)d_in[4];
  const float* Whh_f = (const float*)d_in[5];
  const float* b_f   = (const float*)d_in[6];
  const float* Wih_b = (const float*)d_in[7];
  const float* Whh_b = (const float*)d_in[8];
  const float* b_b   = (const float*)d_in[9];
  const float* Wfc   = (const float*)d_in[10];
  const float* st    = (const float*)d_in[11];
  const float* en    = (const float*)d_in[12];
  const float* trans = (const float*)d_in[13];
  float* out = (float*)d_out;

  char* ws = (char*)d_ws;                         // total required ~91.7 MB
  short* WpackX   = (short*)(ws + 0);             // 2,097,152
  short* WpackH   = (short*)(ws + 2097152);       // 4,194,304
  short* WfcPack  = (short*)(ws + 6291456);       //    32,768
  short* xpack    = (short*)(ws + 6324224);       // 16,777,216
  short* hping    = (short*)(ws + 23101440);      //   262,144
  int*   flags    = (int*)  (ws + 23363584);      //       256
  float* partials = (float*)(ws + 23363840);      //       256
  float* logits   = (float*)(ws + 23364096);      // 1,179,648
  short* hhist    = (short*)(ws + 24543744);      // 67,108,864 -> end 91,652,608

  pack_weights<<<64, 256, 0, stream>>>(Wih_f, Whh_f, Wih_b, Whh_b, Wfc,
                                       WpackX, WpackH, WfcPack);
  pack_x<<<4096, 256, 0, stream>>>(x, emb, xpack);
  init_state<<<1, 64, 0, stream>>>(flags);
  lstm_step_kernel<<<64, 256, 0, stream>>>((const short8*)xpack, WpackX, WpackH,
                                           hping, flags, hhist, b_f, b_b, seqln);
  emis_kernel<<<256, 256, 0, stream>>>(hhist, WfcPack, logits);
  crf_kernel<<<64, 64, 0, stream>>>(logits, y, seqln, st, en, trans, partials);
  finalize_kernel<<<1, 64, 0, stream>>>(partials, out);
}

// Round 3
// 4170.570 us; speedup vs baseline: 2.0608x; 1.5817x over previous
//
#include <hip/hip_runtime.h>
#include <hip/hip_bf16.h>

// BiLSTM-CRF loss, MI355X. B=64 T=512 V=30000 E=256 H=512 C=9.
// Round 3: per-wave fine-grained flags consumed per-kc (pipelined straggler
// tolerance), wide sc1 exchange ops (4B stores / 16B loads), barrier-free
// step loop, software-pipelined h-loads with counted vmcnt.

using short8 = __attribute__((ext_vector_type(8))) short;   // 8 x bf16 bits
using f32x4  = __attribute__((ext_vector_type(4))) float;
using i32x4  = __attribute__((ext_vector_type(4))) int;

#define TT 512
#define BB 64

__device__ __forceinline__ unsigned short f2bf(float f) {
  unsigned int u = __builtin_bit_cast(unsigned int, f);
  u += 0x7FFFu + ((u >> 16) & 1u);           // RNE
  return (unsigned short)(u >> 16);
}
__device__ __forceinline__ float bf2f(short s) {
  unsigned int u = ((unsigned int)(unsigned short)s) << 16;
  return __builtin_bit_cast(float, u);
}
__device__ __forceinline__ float fast_rcp(float x) { return __builtin_amdgcn_rcpf(x); }
__device__ __forceinline__ float sigmoid_f(float x) { return fast_rcp(1.f + __expf(-x)); }
__device__ __forceinline__ float tanh_f(float x) {
  float e = __expf(-2.f * fabsf(x));
  float r = (1.f - e) * fast_rcp(1.f + e);
  return copysignf(r, x);
}
#define SEL4(i, a0, a1, a2, a3) ((i)==0?(a0):((i)==1?(a1):((i)==2?(a2):(a3))))

// ---- uncached (coherence-point) ops: sc0 sc1 ----
__device__ __forceinline__ i32x4 load16_sc(const void* p) {      // no wait
  i32x4 r;
  asm volatile("global_load_dwordx4 %0, %1, off sc0 sc1" : "=v"(r) : "v"(p));
  return r;
}
__device__ __forceinline__ i32x4 load16_sc_wait(const void* p) { // self-waiting
  i32x4 r;
  asm volatile("global_load_dwordx4 %0, %1, off sc0 sc1\n\ts_waitcnt vmcnt(0)"
               : "=v"(r) : "v"(p) : "memory");
  return r;
}
__device__ __forceinline__ void store4_sc(void* p, unsigned int v) {
  asm volatile("global_store_dword %0, %1, off sc0 sc1" :: "v"(p), "v"(v) : "memory");
}
#define WAITV(n) do { asm volatile("s_waitcnt vmcnt(" #n ")" ::: "memory"); \
                      __builtin_amdgcn_sched_barrier(0); } while (0)

// ---------------- K0a: pack LSTM + FC weights to bf16 -----------------------
// LSTM col n in [0,64) of block bid (d=bid&1, sl=bid>>1):
//   gate g=n&3, jq=(n>>2)&3, tj=(n>>4)&1, nt=n>>5 -> unit jj = nt*8+jq*2+tj,
//   weight row r = g*512 + sl*16 + jj.  (unit permutation enables 4B h-stores)
__global__ void pack_weights(const float* __restrict__ Wih_f, const float* __restrict__ Whh_f,
                             const float* __restrict__ Wih_b, const float* __restrict__ Whh_b,
                             const float* __restrict__ Wfc,
                             short* __restrict__ WpackX, short* __restrict__ WpackH,
                             short* __restrict__ WfcPack) {
  const int bid = blockIdx.x;
  const int d = bid & 1, sl = bid >> 1;
  const float* Wih = d ? Wih_b : Wih_f;
  const float* Whh = d ? Whh_b : Whh_f;
  for (int idx = threadIdx.x; idx < 64 * 256; idx += 256) {
    int n = idx >> 8, k = idx & 255;
    int g = n & 3, jq = (n >> 2) & 3, tj = (n >> 4) & 1, nt = n >> 5;
    int r = g * 512 + sl * 16 + nt * 8 + jq * 2 + tj;
    WpackX[((size_t)bid * 64 + n) * 256 + k] = (short)f2bf(Wih[(size_t)r * 256 + k]);
  }
  for (int idx = threadIdx.x; idx < 64 * 512; idx += 256) {
    int n = idx >> 9, k = idx & 511;
    int g = n & 3, jq = (n >> 2) & 3, tj = (n >> 4) & 1, nt = n >> 5;
    int r = g * 512 + sl * 16 + nt * 8 + jq * 2 + tj;
    WpackH[((size_t)bid * 64 + n) * 512 + k] = (short)f2bf(Whh[(size_t)r * 512 + k]);
  }
  if (bid == 0) {
    for (int idx = threadIdx.x; idx < 16 * 1024; idx += 256) {
      int c = idx >> 10, k = idx & 1023;
      WfcPack[idx] = (c < 9) ? (short)f2bf(Wfc[c * 1024 + k]) : (short)0;
    }
  }
}

// ---------------- K0b: gather embeddings into MFMA A-fragment layout --------
__global__ void pack_x(const int* __restrict__ x, const float* __restrict__ emb,
                       short* __restrict__ xpack) {
  int gid = blockIdx.x * 256 + threadIdx.x;     // < 1048576
  int lane = gid & 63;
  int kc = (gid >> 6) & 7;
  int mt = (gid >> 9) & 3;
  int t  = gid >> 11;
  int b  = mt * 16 + (lane & 15);
  int k0 = kc * 32 + (lane >> 4) * 8;
  int vid = x[b * TT + t];
  const float* e = emb + (size_t)vid * 256 + k0;
  short8 v;
#pragma unroll
  for (int i = 0; i < 8; ++i) v[i] = (short)f2bf(e[i]);
  *reinterpret_cast<short8*>(xpack + (size_t)gid * 8) = v;
}

// ---------------- K0c: zero flags -------------------------------------------
__global__ void init_state(int* __restrict__ flags) {
  flags[threadIdx.x] = 0;                       // 256 flags
}

// ---------------- K1: persistent flag-synced BiLSTM -------------------------
// 64 WGs x 256 thr. WG: d=bid&1, sl=bid>>1 owns 16 units x 4 gates.
// Wave (mtb=wv&1, nt=wv>>1): rows [mtb*32,+32) x 8 units [sl*16+nt*8,+8).
// flags[d][mtb][g], g = sl*2+nt in [0,64): wave-granular, step-stamped.
// Row halves (mtb) are independent recurrences -> 4 decoupled pipelines.
__launch_bounds__(256, 1)
__global__ void lstm_step_kernel(const short8* __restrict__ xpack,
                                 const short* __restrict__ WpackX,
                                 const short* __restrict__ WpackH,
                                 short* __restrict__ hping,   // [2][2][64][512]
                                 int* __restrict__ flags,     // [2][2][64]
                                 short* __restrict__ hhist,   // [2][512][64][512]
                                 const float* __restrict__ b_f,
                                 const float* __restrict__ b_b,
                                 const int* __restrict__ seq_len) {
  const int bid = blockIdx.x;
  const int d = bid & 1;
  const int sl = bid >> 1;
  const int tid = threadIdx.x;
  const int wv = tid >> 6;
  const int lane = tid & 63;
  const int l15 = lane & 15;
  const int lhi = lane >> 4;
  const int q = lane & 3;          // gate id of this lane's column
  const int jq = l15 >> 2;
  const int mtb = wv & 1;          // wave's row half
  const int nt = wv >> 1;          // wave's 8-unit group
  const int mbase = mtb * 32;
  const int nbase = nt * 32;
  const int ubase = sl * 16 + nt * 8 + jq * 2;   // this lane's unit pair base

  __shared__ short wih[64 * 264];  // Wih slice, padded stride vs bank conflicts
  for (int idx = tid; idx < 64 * 32; idx += 256) {
    int n = idx >> 5, c8 = idx & 31;
    short8 v = *reinterpret_cast<const short8*>(WpackX + ((size_t)bid * 64 + n) * 256 + c8 * 8);
    *reinterpret_cast<short8*>(&wih[n * 264 + c8 * 8]) = v;
  }

  // Whh B-fragments, register-resident for the whole kernel.
  short8 bfh[2][16];
#pragma unroll
  for (int tj = 0; tj < 2; ++tj) {
#pragma unroll
    for (int kc = 0; kc < 16; ++kc) {
      int n = nbase + tj * 16 + l15;
      bfh[tj][kc] = *reinterpret_cast<const short8*>(
          WpackH + ((size_t)bid * 64 + n) * 512 + kc * 32 + lhi * 8);
    }
  }

  const float* bias = d ? b_b : b_f;
  float bi[2], bfg[2], bgg[2], bog[2];
#pragma unroll
  for (int tj = 0; tj < 2; ++tj) {
    int jg = ubase + tj;
    bi[tj]  = bias[jg];
    bfg[tj] = bias[512 + jg];
    bgg[tj] = bias[1024 + jg];
    bog[tj] = bias[1536 + jg];
  }
  int brow[2], Lr[2];
#pragma unroll
  for (int ti = 0; ti < 2; ++ti) {
    brow[ti] = mbase + ti * 16 + lhi * 4 + q;   // this lane's batch row
    Lr[ti] = seq_len[brow[ti]];
  }
  float cst[2][2] = {{0.f, 0.f}, {0.f, 0.f}};
  float hst[2][2] = {{0.f, 0.f}, {0.f, 0.f}};

  int* fl_mine = flags + (d * 2 + mtb) * 64 + (sl * 2 + nt);  // this wave's flag
  const int* fl_base = flags + (d * 2 + mtb) * 64;            // flags this wave polls
  __syncthreads();   // wih ready; no further barriers in the loop

  for (int s = 0; s < TT; ++s) {
    const int t = d ? (TT - 1 - s) : s;
    f32x4 acc[2][2];
#pragma unroll
    for (int ti = 0; ti < 2; ++ti)
#pragma unroll
      for (int tj = 0; tj < 2; ++tj) acc[ti][tj] = (f32x4){0.f, 0.f, 0.f, 0.f};

    // ---- x@Wih^T : no sequential dependency ----
    const short8* xp = xpack + (size_t)t * 2048;
#pragma unroll
    for (int kc = 0; kc < 8; ++kc) {
      short8 af[2], bf[2];
#pragma unroll
      for (int ti = 0; ti < 2; ++ti) {
        int mtile = mtb * 2 + ti;
        af[ti] = xp[(mtile * 8 + kc) * 64 + lane];
      }
#pragma unroll
      for (int tj = 0; tj < 2; ++tj) {
        int n = nbase + tj * 16 + l15;
        bf[tj] = *reinterpret_cast<const short8*>(&wih[n * 264 + kc * 32 + lhi * 8]);
      }
#pragma unroll
      for (int ti = 0; ti < 2; ++ti)
#pragma unroll
        for (int tj = 0; tj < 2; ++tj)
          acc[ti][tj] = __builtin_amdgcn_mfma_f32_16x16x32_bf16(af[ti], bf[tj], acc[ti][tj], 0, 0, 0);
    }

    if (s > 0) {
      // ---- wait for the 64 producer waves of my (dir,row-half) ----
      {
        const int* myq = fl_base + (lane & 15) * 4;
        int vtries = 0;
        while (true) {
          i32x4 f = load16_sc_wait(myq);
          bool ok = (f[0] >= s) & (f[1] >= s) & (f[2] >= s) & (f[3] >= s);
          if (__all(ok)) break;
          __builtin_amdgcn_s_sleep(1);
          if (++vtries > (1 << 17)) break;     // anti-hang valve
        }
      }
      __builtin_amdgcn_sched_barrier(0);

      // ---- h@Whh^T : 4 groups of 4 kc, 2-deep pipelined sc1 loads ----
      const short* hp = hping + ((size_t)(d * 2 + (s & 1)) * 64) * 512;
      i32x4 lda[8], ldb[8];
#define ISSUE_GRP(grp, dst)                                                     \
  _Pragma("unroll")                                                             \
  for (int kk = 0; kk < 4; ++kk) {                                              \
    int kc = (grp) * 4 + kk;                                                    \
    _Pragma("unroll")                                                           \
    for (int ti = 0; ti < 2; ++ti)                                              \
      dst[kk * 2 + ti] =                                                        \
          load16_sc(hp + (mbase + ti * 16 + l15) * 512 + kc * 32 + lhi * 8);    \
  }
#define MFMA_GRP(grp, src)                                                      \
  _Pragma("unroll")                                                             \
  for (int kk = 0; kk < 4; ++kk) {                                              \
    int kc = (grp) * 4 + kk;                                                    \
    _Pragma("unroll")                                                           \
    for (int ti = 0; ti < 2; ++ti) {                                            \
      short8 a = __builtin_bit_cast(short8, src[kk * 2 + ti]);                  \
      _Pragma("unroll")                                                         \
      for (int tj = 0; tj < 2; ++tj)                                            \
        acc[ti][tj] =                                                           \
            __builtin_amdgcn_mfma_f32_16x16x32_bf16(a, bfh[tj][kc], acc[ti][tj], 0, 0, 0); \
    }                                                                           \
  }
      ISSUE_GRP(0, lda)
      ISSUE_GRP(1, ldb)
      WAITV(8);
      MFMA_GRP(0, lda)
      ISSUE_GRP(2, lda)
      WAITV(8);
      MFMA_GRP(1, ldb)
      ISSUE_GRP(3, ldb)
      WAITV(8);
      MFMA_GRP(2, lda)
      WAITV(0);
      MFMA_GRP(3, ldb)
    }

    // ---- epilogue: gather i,f,g,o via 4-lane shuffles, update state ----
    short* hpo = hping + ((size_t)(d * 2 + ((s + 1) & 1)) * 64) * 512;
    unsigned int hh32[2];
#pragma unroll
    for (int ti = 0; ti < 2; ++ti) {
      bool m = (t < Lr[ti]);
      unsigned short hnb[2], htb[2];
#pragma unroll
      for (int tj = 0; tj < 2; ++tj) {
        f32x4 A = acc[ti][tj];
        float a0 = A[0], a1 = A[1], a2 = A[2], a3 = A[3];
        float e10 = __shfl_xor(a0, 1, 64), e11 = __shfl_xor(a1, 1, 64),
              e12 = __shfl_xor(a2, 1, 64), e13 = __shfl_xor(a3, 1, 64);
        float e20 = __shfl_xor(a0, 2, 64), e21 = __shfl_xor(a1, 2, 64),
              e22 = __shfl_xor(a2, 2, 64), e23 = __shfl_xor(a3, 2, 64);
        float e30 = __shfl_xor(a0, 3, 64), e31 = __shfl_xor(a1, 3, 64),
              e32 = __shfl_xor(a2, 3, 64), e33 = __shfl_xor(a3, 3, 64);
        float g0 = SEL4(q, a0, a1, a2, a3);
        float g1 = SEL4(q, e10, e11, e12, e13);
        float g2 = SEL4(q, e20, e21, e22, e23);
        float g3 = SEL4(q, e30, e31, e32, e33);
        float gi = SEL4(q,     g0, g1, g2, g3) + bi[tj];
        float gf = SEL4(q ^ 1, g0, g1, g2, g3) + bfg[tj];
        float gg = SEL4(q ^ 2, g0, g1, g2, g3) + bgg[tj];
        float go = SEL4(q ^ 3, g0, g1, g2, g3) + bog[tj];
        float si = sigmoid_f(gi), sf = sigmoid_f(gf), so = sigmoid_f(go);
        float ct = sf * cst[ti][tj] + si * tanh_f(gg);
        float ht = so * tanh_f(ct);
        float cn = m ? ct : cst[ti][tj];
        float hn = m ? ht : hst[ti][tj];
        cst[ti][tj] = cn;
        hst[ti][tj] = hn;
        hnb[tj] = f2bf(hn);
        htb[tj] = m ? f2bf(ht) : (unsigned short)0;
      }
      unsigned int up = ((unsigned int)hnb[1] << 16) | hnb[0];
      store4_sc(hpo + brow[ti] * 512 + ubase, up);                 // frozen carry
      hh32[ti] = ((unsigned int)htb[1] << 16) | htb[0];
    }
    // publish this wave's flag after its h-stores are globally visible
    if (lane == 0) {
      int sv = s + 1;
      asm volatile("s_waitcnt vmcnt(0)\n\t"
                   "global_store_dword %0, %1, off sc0 sc1"
                   :: "v"(fl_mine), "v"(sv) : "memory");
    }
    // masked history (off critical path, normal cached stores)
#pragma unroll
    for (int ti = 0; ti < 2; ++ti)
      *reinterpret_cast<unsigned int*>(
          &hhist[(((size_t)d * TT + t) * 64 + brow[ti]) * 512 + ubase]) = hh32[ti];
  }
}

// ---------------- K2: emission logits = [hf|hb] @ Wfc^T via MFMA ------------
__launch_bounds__(256)
__global__ void emis_kernel(const short* __restrict__ hhist,
                            const short* __restrict__ WfcPack,
                            float* __restrict__ logits) {
  __shared__ short wfc[16 * 1032];             // padded stride vs bank conflicts
  const int tid = threadIdx.x;
  for (int idx = tid; idx < 2048; idx += 256) {
    int n = idx >> 7, c8 = idx & 127;
    short8 v = *reinterpret_cast<const short8*>(WfcPack + n * 1024 + c8 * 8);
    *reinterpret_cast<short8*>(&wfc[n * 1032 + c8 * 8]) = v;
  }
  __syncthreads();
  const int wv = tid >> 6, lane = tid & 63;
  const int l15 = lane & 15, lhi = lane >> 4;
#pragma unroll
  for (int mt2 = 0; mt2 < 2; ++mt2) {
    int m = (blockIdx.x * 4 + wv) * 2 + mt2;
    int r0 = m * 16;
    f32x4 acc = (f32x4){0.f, 0.f, 0.f, 0.f};
#pragma unroll
    for (int kc = 0; kc < 32; ++kc) {
      const short* pa = hhist + ((kc < 16) ? 0 : (size_t)16777216)
                        + (size_t)(r0 + l15) * 512 + (kc & 15) * 32 + lhi * 8;
      short8 a = *reinterpret_cast<const short8*>(pa);
      short8 b = *reinterpret_cast<const short8*>(&wfc[l15 * 1032 + kc * 32 + lhi * 8]);
      acc = __builtin_amdgcn_mfma_f32_16x16x32_bf16(a, b, acc, 0, 0, 0);
    }
    int c = l15;
    if (c < 9) {
#pragma unroll
      for (int reg = 0; reg < 4; ++reg) {
        int rr = r0 + lhi * 4 + reg;
        int b = rr & 63, t = rr >> 6;
        logits[((size_t)b * TT + t) * 9 + c] = acc[reg];
      }
    }
  }
}

// ---------------- K3: CRF numerator + forward algorithm per batch -----------
__global__ void crf_kernel(const float* __restrict__ logits, const int* __restrict__ y,
                           const int* __restrict__ seq_len, const float* __restrict__ start_t,
                           const float* __restrict__ end_t, const float* __restrict__ trans,
                           float* __restrict__ partials) {
  const int b = blockIdx.x;
  const int lane = threadIdx.x;          // 64
  const float* lg = logits + (size_t)b * TT * 9;
  const int* yb = y + b * TT;
  const int L = seq_len[b];

  float acc = 0.f;
  for (int t = lane; t < TT; t += 64) {
    if (t < L) {
      float mx = lg[t * 9];
      for (int c = 1; c < 9; ++c) mx = fmaxf(mx, lg[t * 9 + c]);
      float se = 0.f;
      for (int c = 0; c < 9; ++c) se += __expf(lg[t * 9 + c] - mx);
      float lse = mx + __logf(se);
      int yt = yb[t];
      acc += lg[t * 9 + yt] - lse;
      if (t >= 1) acc += trans[yb[t - 1] * 9 + yt];
    }
  }
#pragma unroll
  for (int off = 32; off >= 1; off >>= 1) acc += __shfl_down(acc, off, 64);

  const int c = (lane < 9) ? lane : 0;
  float score;
  {
    float mx = lg[0];
    for (int cc = 1; cc < 9; ++cc) mx = fmaxf(mx, lg[cc]);
    float se = 0.f;
    for (int cc = 0; cc < 9; ++cc) se += __expf(lg[cc] - mx);
    score = start_t[c] + lg[c] - (mx + __logf(se));
  }
  float tr[9];
#pragma unroll
  for (int cc = 0; cc < 9; ++cc) tr[cc] = trans[cc * 9 + c];
  for (int t = 1; t < L; ++t) {
    const float* lt = lg + t * 9;
    float mx2 = lt[0];
    for (int cc = 1; cc < 9; ++cc) mx2 = fmaxf(mx2, lt[cc]);
    float se2 = 0.f;
    for (int cc = 0; cc < 9; ++cc) se2 += __expf(lt[cc] - mx2);
    float em = lt[c] - (mx2 + __logf(se2));
    float vv[9];
    float mx = -1e30f;
#pragma unroll
    for (int cc = 0; cc < 9; ++cc) {
      float sp = __shfl(score, cc, 64);
      vv[cc] = sp + tr[cc];
      mx = fmaxf(mx, vv[cc]);
    }
    float se = 0.f;
#pragma unroll
    for (int cc = 0; cc < 9; ++cc) se += __expf(vv[cc] - mx);
    score = mx + __logf(se) + em;
  }
  float val = (lane < 9) ? (score + end_t[lane]) : -1e30f;
  float mm = val;
#pragma unroll
  for (int off = 1; off < 64; off <<= 1) mm = fmaxf(mm, __shfl_xor(mm, off, 64));
  float se = (lane < 9) ? __expf(val - mm) : 0.f;
#pragma unroll
  for (int off = 1; off < 64; off <<= 1) se += __shfl_xor(se, off, 64);
  float den = mm + __logf(se);
  if (lane == 0) {
    float num = acc + start_t[yb[0]] + end_t[yb[L - 1]];
    partials[b] = num - den;
  }
}

// ---------------- K4: final reduce ------------------------------------------
__global__ void finalize_kernel(const float* __restrict__ partials, float* __restrict__ out) {
  int l = threadIdx.x;
  float v = partials[l];
#pragma unroll
  for (int off = 32; off >= 1; off >>= 1) v += __shfl_down(v, off, 64);
  if (l == 0) out[0] = -v;
}

extern "C" void kernel_launch(void* const* d_in, const int* in_sizes, int n_in,
                              void* d_out, int out_size, void* d_ws, size_t ws_size,
                              hipStream_t stream) {
  const int*   x     = (const int*)d_in[0];
  const int*   seqln = (const int*)d_in[1];
  const int*   y     = (const int*)d_in[2];
  const float* emb   = (const float*)d_in[3];
  const float* Wih_f = (const float*)d_in[4];
  const float* Whh_f = (const float*)d_in[5];
  const float* b_f   = (const float*)d_in[6];
  const float* Wih_b = (const float*)d_in[7];
  const float* Whh_b = (const float*)d_in[8];
  const float* b_b   = (const float*)d_in[9];
  const float* Wfc   = (const float*)d_in[10];
  const float* st    = (const float*)d_in[11];
  const float* en    = (const float*)d_in[12];
  const float* trans = (const float*)d_in[13];
  float* out = (float*)d_out;

  char* ws = (char*)d_ws;                         // total required ~91.7 MB
  short* WpackX   = (short*)(ws + 0);             // 2,097,152
  short* WpackH   = (short*)(ws + 2097152);       // 4,194,304
  short* WfcPack  = (short*)(ws + 6291456);       //    32,768
  short* xpack    = (short*)(ws + 6324224);       // 16,777,216
  short* hping    = (short*)(ws + 23101440);      //   262,144
  int*   flags    = (int*)  (ws + 23363584);      //     1,024
  float* partials = (float*)(ws + 23364608);      //       256
  float* logits   = (float*)(ws + 23364864);      // 1,179,648
  short* hhist    = (short*)(ws + 24544512);      // 67,108,864 -> end 91,653,376

  pack_weights<<<64, 256, 0, stream>>>(Wih_f, Whh_f, Wih_b, Whh_b, Wfc,
                                       WpackX, WpackH, WfcPack);
  pack_x<<<4096, 256, 0, stream>>>(x, emb, xpack);
  init_state<<<1, 256, 0, stream>>>(flags);
  lstm_step_kernel<<<64, 256, 0, stream>>>((const short8*)xpack, WpackX, WpackH,
                                           hping, flags, hhist, b_f, b_b, seqln);
  emis_kernel<<<256, 256, 0, stream>>>(hhist, WfcPack, logits);
  crf_kernel<<<64, 64, 0, stream>>>(logits, y, seqln, st, en, trans, partials);
  finalize_kernel<<<1, 64, 0, stream>>>(partials, out);
}